// Round 2
// baseline (5599.450 us; speedup 1.0000x reference)
//
#include <hip/hip_runtime.h>
#include <hip/hip_bf16.h>
#include <math.h>

#define S_ 2048
#define B_ 4
#define D_ 1024
#define H_ 16
#define HD_ 64
#define NB_ 127
#define WIN_ 512
#define NSEL_ 16
#define SELBLK_ 64
#define SCALE_ 0.125f

// ---------------- generic tiled fp32 GEMM: C = A @ B^T + bias ----------------
// A: M x K row-major (AMODE=1: A is (B_*S_) x 1024 k/v tokens, cols 1024..1026 come from positions)
// Bm: N x K row-major
// EPI: 0 = plain store, 1 = relu store, 2 = qkv scatter (gm = s*B+b, gn in [0,3072))
template<int AMODE, int EPI>
__launch_bounds__(256)
__global__ void gemm_kernel(const float* __restrict__ A, const float* __restrict__ Bm,
                            const float* __restrict__ bias, float* __restrict__ C,
                            int M, int N, int K,
                            const float* __restrict__ pos,
                            float* __restrict__ q_tok, float* __restrict__ k_tok,
                            float* __restrict__ v_tok)
{
    __shared__ float As[16][68];
    __shared__ float Bs[16][68];
    const int tid = threadIdx.x;
    const int tx = tid & 15, ty = tid >> 4;
    const int bm = blockIdx.x * 64, bn = blockIdx.y * 64;
    float acc[4][4] = {};
    for (int k0 = 0; k0 < K; k0 += 16) {
#pragma unroll
        for (int l = 0; l < 4; ++l) {
            int t = tid + l * 256;
            int m = t >> 4, kk = t & 15;
            int gm = bm + m, gk = k0 + kk;
            float av = 0.f;
            if (gm < M && gk < K) {
                if (AMODE == 0) av = A[(size_t)gm * K + gk];
                else av = (gk < D_) ? A[(size_t)gm * D_ + gk]
                                    : pos[(gm % S_) * 3 + (gk - D_)];
            }
            As[kk][m] = av;
            int gn = bn + m;
            float bv = 0.f;
            if (gn < N && gk < K) bv = Bm[(size_t)gn * K + gk];
            Bs[kk][m] = bv;
        }
        __syncthreads();
#pragma unroll
        for (int kk = 0; kk < 16; ++kk) {
            float a[4], b[4];
#pragma unroll
            for (int i = 0; i < 4; ++i) a[i] = As[kk][ty * 4 + i];
#pragma unroll
            for (int j = 0; j < 4; ++j) b[j] = Bs[kk][tx * 4 + j];
#pragma unroll
            for (int i = 0; i < 4; ++i)
#pragma unroll
                for (int j = 0; j < 4; ++j)
                    acc[i][j] = fmaf(a[i], b[j], acc[i][j]);
        }
        __syncthreads();
    }
#pragma unroll
    for (int i = 0; i < 4; ++i) {
        int gm = bm + ty * 4 + i;
        if (gm >= M) continue;
#pragma unroll
        for (int j = 0; j < 4; ++j) {
            int gn = bn + tx * 4 + j;
            if (gn >= N) continue;
            float v = acc[i][j] + bias[gn];
            if (EPI == 0) {
                C[(size_t)gm * N + gn] = v;
            } else if (EPI == 1) {
                C[(size_t)gm * N + gn] = fmaxf(v, 0.f);
            } else {
                int s = gm / B_, b = gm % B_;
                int h = gn / 192, r = gn - h * 192;
                int c = h * 64 + (r & 63);
                size_t off = ((size_t)b * S_ + s) * (size_t)D_ + c;
                if (r < 64) q_tok[off] = v;
                else if (r < 128) k_tok[off] = v;
                else v_tok[off] = v;
            }
        }
    }
}

// cpre[b,n,c] = mean_{j<32} rg[b, n*16+j, c]
__global__ void block_mean_kernel(const float* __restrict__ rg, float* __restrict__ cpre)
{
    int bn = blockIdx.x;
    int b = bn / NB_, n = bn % NB_;
    int s0 = n * 16;
    for (int c = threadIdx.x; c < D_; c += 256) {
        float sum = 0.f;
        for (int j = 0; j < 32; ++j)
            sum += rg[((size_t)b * S_ + s0 + j) * D_ + c];
        cpre[(size_t)bn * D_ + c] = sum * (1.f / 32.f);
    }
}

// q_mean_s[b,h,d] = mean_s q_tok[b,s,h*64+d]   (grid B*H, 256 threads)
__global__ void mean_qs_kernel(const float* __restrict__ q_tok, float* __restrict__ q_mean_s)
{
    int bh = blockIdx.x;
    int b = bh >> 4, h = bh & 15;
    int t = threadIdx.x, d = t & 63, sg = t >> 6;
    float sum = 0.f;
    for (int s = sg; s < S_; s += 4)
        sum += q_tok[((size_t)b * S_ + s) * D_ + (h << 6) + d];
    __shared__ float red[4][64];
    red[sg][d] = sum;
    __syncthreads();
    if (sg == 0)
        q_mean_s[bh * 64 + d] = (red[0][d] + red[1][d] + red[2][d] + red[3][d]) * (1.f / S_);
}

// q_mean_h[b,s,d] = mean_h q_tok[b,s,h*64+d]  (double) (grid B*S, 64 threads)
__global__ void mean_qh_kernel(const float* __restrict__ q_tok, double* __restrict__ q_mean_h)
{
    size_t bs = blockIdx.x;
    int d = threadIdx.x;
    double sum = 0.0;
    for (int h = 0; h < H_; ++h) sum += (double)q_tok[bs * D_ + h * 64 + d];
    q_mean_h[bs * 64 + d] = sum * (1.0 / H_);
}

// ckm[b,n,d] = mean_h cmp_k[b,n,h*64+d]  (double) (grid B*NB, 64 threads)
__global__ void mean_ckh_kernel(const float* __restrict__ cmp_k, double* __restrict__ ckm)
{
    size_t bn = blockIdx.x;
    int d = threadIdx.x;
    double sum = 0.0;
    for (int h = 0; h < H_; ++h) sum += (double)cmp_k[bn * D_ + h * 64 + d];
    ckm[bn * 64 + d] = sum * (1.0 / H_);
}

// out_cmp[b,h,:] = softmax(q_mean_s . cmp_k * SCALE) @ cmp_v   (grid B*H, 128 threads)
__launch_bounds__(128)
__global__ void out_cmp_kernel(const float* __restrict__ q_mean_s, const float* __restrict__ cmp_k,
                               const float* __restrict__ cmp_v, float* __restrict__ out_cmp)
{
    int bh = blockIdx.x;
    int b = bh >> 4, h = bh & 15;
    int t = threadIdx.x;
    __shared__ float qv[64];
    __shared__ float pv[128];
    __shared__ float red[128];
    if (t < 64) qv[t] = q_mean_s[bh * 64 + t];
    __syncthreads();
    float sc = -1e30f;
    if (t < NB_) {
        const float* kr = &cmp_k[((size_t)b * NB_ + t) * D_ + h * HD_];
        float sum = 0.f;
        for (int d = 0; d < 64; ++d) sum = fmaf(qv[d], kr[d], sum);
        sc = sum * SCALE_;
    }
    red[t] = sc;
    __syncthreads();
    for (int off = 64; off > 0; off >>= 1) {
        if (t < off) red[t] = fmaxf(red[t], red[t + off]);
        __syncthreads();
    }
    float mx = red[0];
    __syncthreads();
    float e = (t < NB_) ? __expf(sc - mx) : 0.f;
    pv[t] = e;
    red[t] = e;
    __syncthreads();
    for (int off = 64; off > 0; off >>= 1) {
        if (t < off) red[t] += red[t + off];
        __syncthreads();
    }
    float sm = red[0];
    __syncthreads();
    if (t < 64) {
        float o = 0.f;
        for (int n = 0; n < NB_; ++n)
            o = fmaf(pv[n], cmp_v[((size_t)b * NB_ + n) * D_ + h * HD_ + t], o);
        out_cmp[bh * 64 + t] = o / sm;
    }
}

// imp_all[b,n,s] = softmax_n(q_mean_h[b,s] . ckm[b,n] * SCALE)  fp64  (grid B*S, 128 thr)
__launch_bounds__(128)
__global__ void imp1_kernel(const double* __restrict__ q_mean_h, const double* __restrict__ ckm,
                            double* __restrict__ imp_all)
{
    int bs = blockIdx.x;
    int b = bs >> 11, s = bs & (S_ - 1);
    int t = threadIdx.x;
    __shared__ double qv[64];
    __shared__ double red[128];
    if (t < 64) qv[t] = q_mean_h[(size_t)bs * 64 + t];
    __syncthreads();
    double sc = -1e300;
    if (t < NB_) {
        const double* kr = &ckm[(b * NB_ + t) * 64];
        double sum = 0.0;
        for (int d = 0; d < 64; ++d) sum = fma(qv[d], kr[d], sum);
        sc = sum * (double)SCALE_;
    }
    red[t] = sc;
    __syncthreads();
    for (int off = 64; off > 0; off >>= 1) {
        if (t < off) red[t] = fmax(red[t], red[t + off]);
        __syncthreads();
    }
    double mx = red[0];
    __syncthreads();
    double e = (t < NB_) ? exp(sc - mx) : 0.0;
    red[t] = e;
    __syncthreads();
    for (int off = 64; off > 0; off >>= 1) {
        if (t < off) red[t] += red[t + off];
        __syncthreads();
    }
    double sm = red[0];
    if (t < NB_) imp_all[((size_t)(b * NB_ + t)) * S_ + s] = e / sm;
}

// imp[b,n] = mean_s imp_all[b,n,s]  fp64  (grid B*NB, 256 threads)
__global__ void imp2_kernel(const double* __restrict__ imp_all, double* __restrict__ imp)
{
    int bn = blockIdx.x;
    int t = threadIdx.x;
    double sum = 0.0;
    for (int s = t; s < S_; s += 256) sum += imp_all[(size_t)bn * S_ + s];
    __shared__ double red[256];
    red[t] = sum;
    __syncthreads();
    for (int off = 128; off > 0; off >>= 1) {
        if (t < off) red[t] += red[t + off];
        __syncthreads();
    }
    if (t == 0) imp[bn] = red[0] * (1.0 / S_);
}

// exact top-16 per batch, stable (lowest index wins ties) — matches jax.lax.top_k
__global__ void topk_kernel(const double* __restrict__ imp, int* __restrict__ topb)
{
    int b = threadIdx.x;
    if (b >= B_) return;
    unsigned long long used0 = 0ull, used1 = 0ull;
    for (int m = 0; m < NSEL_; ++m) {
        double best = -1e300;
        int bi = 0;
        for (int n = 0; n < NB_; ++n) {
            bool u = (n < 64) ? ((used0 >> n) & 1ull) : ((used1 >> (n - 64)) & 1ull);
            double v = imp[b * NB_ + n];
            if (!u && v > best) { best = v; bi = n; }
        }
        if (bi < 64) used0 |= 1ull << bi; else used1 |= 1ull << (bi - 64);
        topb[b * NSEL_ + m] = bi;
    }
}

// flash attention, one wave per query; K/V staged in LDS chunks of 64 keys.
// MODE 0: window (last NKEYS tokens). MODE 1: selected blocks (chunk c == block c).
template<int NKEYS, int MODE>
__launch_bounds__(256)
__global__ void attn_kernel(const float* __restrict__ q_tok, const float* __restrict__ k_tok,
                            const float* __restrict__ v_tok, const int* __restrict__ topb,
                            float* __restrict__ outp)
{
    constexpr int NCH = NKEYS / 64;
    __shared__ float klds[64 * 65];
    __shared__ float vlds[64 * 65];
    __shared__ float pbuf[4][64];
    __shared__ float qbuf[4][64];
    __shared__ int selb[NSEL_];
    const int tid = threadIdx.x;
    const int wid = tid >> 6, lane = tid & 63;
    const int gq0 = blockIdx.x * 4;
    const int b = gq0 >> 15;
    const int h = (gq0 >> 11) & (H_ - 1);
    const int s = (gq0 & (S_ - 1)) + wid;
    qbuf[wid][lane] = q_tok[((size_t)b * S_ + s) * D_ + h * HD_ + lane];
    if (MODE == 1 && tid < NSEL_) selb[tid] = topb[b * NSEL_ + tid];
    float rm = -1e30f, rs = 0.f, o = 0.f;
    for (int c = 0; c < NCH; ++c) {
        __syncthreads();  // prev-iter LDS reads done; qbuf/selb visible on first iter
        for (int i = tid; i < 64 * 64; i += 256) {
            int r = i >> 6, d = i & 63;
            int t;
            if (MODE == 0) {
                t = S_ - NKEYS + c * 64 + r;
            } else {
                int tt = selb[c] * SELBLK_ + r;
                t = (tt < S_) ? tt : (S_ - 1);
            }
            size_t base = ((size_t)b * S_ + t) * D_ + h * HD_ + d;
            klds[r * 65 + d] = k_tok[base];
            vlds[r * 65 + d] = v_tok[base];
        }
        __syncthreads();
        float sc = 0.f;
#pragma unroll 8
        for (int d = 0; d < 64; ++d)
            sc = fmaf(qbuf[wid][d], klds[lane * 65 + d], sc);
        sc *= SCALE_;
        float cm = sc;
#pragma unroll
        for (int off = 32; off > 0; off >>= 1)
            cm = fmaxf(cm, __shfl_xor(cm, off, 64));
        float nm = fmaxf(rm, cm);
        float alpha = __expf(rm - nm);
        float p = __expf(sc - nm);
        float ps = p;
#pragma unroll
        for (int off = 32; off > 0; off >>= 1)
            ps += __shfl_xor(ps, off, 64);
        rs = rs * alpha + ps;
        o *= alpha;
        rm = nm;
        pbuf[wid][lane] = p;
        __syncthreads();
#pragma unroll 8
        for (int r = 0; r < 64; ++r)
            o = fmaf(pbuf[wid][r], vlds[r * 65 + lane], o);
    }
    outp[((size_t)b * S_ + s) * D_ + h * HD_ + lane] = o / rs;
}

// gates = softmax([oc,osl,ow] @ w_g.T + b_g); out = g0*oc+g1*osl+g2*ow  (grid B*S, 128 thr)
__launch_bounds__(128)
__global__ void gate_kernel(const float* __restrict__ out_cmp, const float* __restrict__ o_slc,
                            const float* __restrict__ o_win, const float* __restrict__ w_g,
                            const float* __restrict__ b_g, float* __restrict__ outp)
{
    int bs = blockIdx.x;
    int b = bs >> 11;
    int t = threadIdx.x;
    float oc_r[8], os_r[8], ow_r[8];
    float g0 = 0.f, g1 = 0.f, g2 = 0.f;
#pragma unroll
    for (int i = 0; i < 8; ++i) {
        int c = t + i * 128;
        float oc = out_cmp[(b * H_ + (c >> 6)) * 64 + (c & 63)];
        float os = o_slc[(size_t)bs * D_ + c];
        float ow = o_win[(size_t)bs * D_ + c];
        oc_r[i] = oc; os_r[i] = os; ow_r[i] = ow;
        g0 += w_g[c] * oc + w_g[1024 + c] * os + w_g[2048 + c] * ow;
        g1 += w_g[3072 + c] * oc + w_g[3072 + 1024 + c] * os + w_g[3072 + 2048 + c] * ow;
        g2 += w_g[6144 + c] * oc + w_g[6144 + 1024 + c] * os + w_g[6144 + 2048 + c] * ow;
    }
    __shared__ float red[3][128];
    red[0][t] = g0; red[1][t] = g1; red[2][t] = g2;
    __syncthreads();
    for (int off = 64; off > 0; off >>= 1) {
        if (t < off) {
            red[0][t] += red[0][t + off];
            red[1][t] += red[1][t + off];
            red[2][t] += red[2][t + off];
        }
        __syncthreads();
    }
    float a0 = red[0][0] + b_g[0], a1 = red[1][0] + b_g[1], a2 = red[2][0] + b_g[2];
    float m = fmaxf(a0, fmaxf(a1, a2));
    float e0 = __expf(a0 - m), e1 = __expf(a1 - m), e2 = __expf(a2 - m);
    float inv = 1.f / (e0 + e1 + e2);
    e0 *= inv; e1 *= inv; e2 *= inv;
#pragma unroll
    for (int i = 0; i < 8; ++i) {
        int c = t + i * 128;
        outp[(size_t)bs * D_ + c] = e0 * oc_r[i] + e1 * os_r[i] + e2 * ow_r[i];
    }
}

extern "C" void kernel_launch(void* const* d_in, const int* in_sizes, int n_in,
                              void* d_out, int out_size, void* d_ws, size_t ws_size,
                              hipStream_t stream)
{
    const float* x     = (const float*)d_in[0];
    const float* pos   = (const float*)d_in[1];
    const float* w_qkv = (const float*)d_in[2];
    const float* b_qkv = (const float*)d_in[3];
    const float* w_c1  = (const float*)d_in[4];
    const float* b_c1  = (const float*)d_in[5];
    const float* w_c2  = (const float*)d_in[6];
    const float* b_c2  = (const float*)d_in[7];
    const float* w_g   = (const float*)d_in[8];
    const float* b_g   = (const float*)d_in[9];
    float* out = (float*)d_out;
    (void)in_sizes; (void)n_in; (void)out_size; (void)ws_size;

    char* wp = (char*)d_ws;
    size_t off = 0;
    auto alloc = [&](size_t nbytes) -> void* {
        void* p = (void*)(wp + off);
        off += ((nbytes + 255) / 256) * 256;
        return p;
    };
    const size_t NTOK = (size_t)B_ * S_ * D_;          // 8,388,608
    float* q_tok = (float*)alloc(NTOK * 4);
    float* k_tok = (float*)alloc(NTOK * 4);
    float* v_tok = (float*)alloc(NTOK * 4);
    float* o_slc = (float*)alloc(NTOK * 4);   // early life: rg (relu'd c1 output)
    float* o_win = (float*)alloc(NTOK * 4);   // early life: imp_all (fp64)
    float*  rg      = o_slc;
    double* imp_all = (double*)o_win;         // B*NB*S doubles = 8.3 MB < 32 MB
    float* cpre_k = (float*)alloc((size_t)B_ * NB_ * D_ * 4);
    float* cpre_v = (float*)alloc((size_t)B_ * NB_ * D_ * 4);
    float* cmp_k  = (float*)alloc((size_t)B_ * NB_ * D_ * 4);
    float* cmp_v  = (float*)alloc((size_t)B_ * NB_ * D_ * 4);
    float*  q_mean_s = (float*)alloc(B_ * H_ * 64 * 4);
    double* q_mean_h = (double*)alloc((size_t)B_ * S_ * 64 * 8);
    double* ckm  = (double*)alloc(B_ * NB_ * 64 * 8);
    float*  ocmp = (float*)alloc(B_ * H_ * 64 * 4);
    double* imp  = (double*)alloc(B_ * NB_ * 8);
    int*    topb = (int*)alloc(B_ * NSEL_ * 4);

    dim3 blk(256);
    // 1. QKV projection + scatter to head-major token layouts
    gemm_kernel<0, 2><<<dim3(128, 48), blk, 0, stream>>>(
        x, w_qkv, b_qkv, nullptr, S_ * B_, 3 * D_, D_, nullptr, q_tok, k_tok, v_tok);
    // 2. compression: per-token c1+relu, block mean, c2
    gemm_kernel<1, 1><<<dim3(128, 16), blk, 0, stream>>>(
        k_tok, w_c1, b_c1, rg, B_ * S_, D_, D_ + 3, pos, nullptr, nullptr, nullptr);
    block_mean_kernel<<<B_ * NB_, blk, 0, stream>>>(rg, cpre_k);
    gemm_kernel<1, 1><<<dim3(128, 16), blk, 0, stream>>>(
        v_tok, w_c1, b_c1, rg, B_ * S_, D_, D_ + 3, pos, nullptr, nullptr, nullptr);
    block_mean_kernel<<<B_ * NB_, blk, 0, stream>>>(rg, cpre_v);
    gemm_kernel<0, 0><<<dim3(8, 16), blk, 0, stream>>>(
        cpre_k, w_c2, b_c2, cmp_k, B_ * NB_, D_, D_, nullptr, nullptr, nullptr, nullptr);
    gemm_kernel<0, 0><<<dim3(8, 16), blk, 0, stream>>>(
        cpre_v, w_c2, b_c2, cmp_v, B_ * NB_, D_, D_, nullptr, nullptr, nullptr, nullptr);
    // 3. means
    mean_qs_kernel<<<B_ * H_, blk, 0, stream>>>(q_tok, q_mean_s);
    mean_qh_kernel<<<B_ * S_, 64, 0, stream>>>(q_tok, q_mean_h);
    mean_ckh_kernel<<<B_ * NB_, 64, 0, stream>>>(cmp_k, ckm);
    // 4. compressed-branch attention + importance (fp64) + top-k
    out_cmp_kernel<<<B_ * H_, 128, 0, stream>>>(q_mean_s, cmp_k, cmp_v, ocmp);
    imp1_kernel<<<B_ * S_, 128, 0, stream>>>(q_mean_h, ckm, imp_all);
    imp2_kernel<<<B_ * NB_, 256, 0, stream>>>(imp_all, imp);
    topk_kernel<<<1, 64, 0, stream>>>(imp, topb);
    // 5. selected + window attention
    attn_kernel<1024, 1><<<32768, blk, 0, stream>>>(q_tok, k_tok, v_tok, topb, o_slc);
    attn_kernel<512, 0><<<32768, blk, 0, stream>>>(q_tok, k_tok, v_tok, nullptr, o_win);
    // 6. gate + combine
    gate_kernel<<<B_ * S_, 128, 0, stream>>>(ocmp, o_slc, o_win, w_g, b_g, out);
}

// Round 3
// 2445.074 us; speedup vs baseline: 2.2901x; 2.2901x over previous
//
#include <hip/hip_runtime.h>
#include <hip/hip_bf16.h>
#include <math.h>

#define S_ 2048
#define B_ 4
#define D_ 1024
#define H_ 16
#define HD_ 64
#define NB_ 127
#define WIN_ 512
#define NSEL_ 16
#define SELBLK_ 64
#define SCALE_ 0.125f

typedef __attribute__((ext_vector_type(8))) short short8;
typedef __attribute__((ext_vector_type(4))) float f32x4;

__device__ inline short f2bf(float f) {
    __hip_bfloat16 h = __float2bfloat16(f);
    return *reinterpret_cast<short*>(&h);
}

// ---------------- generic tiled fp32 GEMM: C = A @ B^T + bias ----------------
// (unchanged from R2 — needed in fp32 so the fp64 importance/top-k chain stays exact)
template<int AMODE, int EPI>
__launch_bounds__(256)
__global__ void gemm_kernel(const float* __restrict__ A, const float* __restrict__ Bm,
                            const float* __restrict__ bias, float* __restrict__ C,
                            int M, int N, int K,
                            const float* __restrict__ pos,
                            float* __restrict__ q_tok, float* __restrict__ k_tok,
                            float* __restrict__ v_tok)
{
    __shared__ float As[16][68];
    __shared__ float Bs[16][68];
    const int tid = threadIdx.x;
    const int tx = tid & 15, ty = tid >> 4;
    const int bm = blockIdx.x * 64, bn = blockIdx.y * 64;
    float acc[4][4] = {};
    for (int k0 = 0; k0 < K; k0 += 16) {
#pragma unroll
        for (int l = 0; l < 4; ++l) {
            int t = tid + l * 256;
            int m = t >> 4, kk = t & 15;
            int gm = bm + m, gk = k0 + kk;
            float av = 0.f;
            if (gm < M && gk < K) {
                if (AMODE == 0) av = A[(size_t)gm * K + gk];
                else av = (gk < D_) ? A[(size_t)gm * D_ + gk]
                                    : pos[(gm % S_) * 3 + (gk - D_)];
            }
            As[kk][m] = av;
            int gn = bn + m;
            float bv = 0.f;
            if (gn < N && gk < K) bv = Bm[(size_t)gn * K + gk];
            Bs[kk][m] = bv;
        }
        __syncthreads();
#pragma unroll
        for (int kk = 0; kk < 16; ++kk) {
            float a[4], b[4];
#pragma unroll
            for (int i = 0; i < 4; ++i) a[i] = As[kk][ty * 4 + i];
#pragma unroll
            for (int j = 0; j < 4; ++j) b[j] = Bs[kk][tx * 4 + j];
#pragma unroll
            for (int i = 0; i < 4; ++i)
#pragma unroll
                for (int j = 0; j < 4; ++j)
                    acc[i][j] = fmaf(a[i], b[j], acc[i][j]);
        }
        __syncthreads();
    }
#pragma unroll
    for (int i = 0; i < 4; ++i) {
        int gm = bm + ty * 4 + i;
        if (gm >= M) continue;
#pragma unroll
        for (int j = 0; j < 4; ++j) {
            int gn = bn + tx * 4 + j;
            if (gn >= N) continue;
            float v = acc[i][j] + bias[gn];
            if (EPI == 0) {
                C[(size_t)gm * N + gn] = v;
            } else if (EPI == 1) {
                C[(size_t)gm * N + gn] = fmaxf(v, 0.f);
            } else {
                int s = gm / B_, b = gm % B_;
                int h = gn / 192, r = gn - h * 192;
                int c = h * 64 + (r & 63);
                size_t off = ((size_t)b * S_ + s) * (size_t)D_ + c;
                if (r < 64) q_tok[off] = v;
                else if (r < 128) k_tok[off] = v;
                else v_tok[off] = v;
            }
        }
    }
}

// v_t[b][h][d][s] (bf16) = transpose of v_tok[b][s][h*64+d]
__launch_bounds__(256)
__global__ void vt_kernel(const float* __restrict__ v_tok, unsigned short* __restrict__ v_t)
{
    __shared__ float tile[64][65];
    int blk = blockIdx.x;                 // b*512 + h*32 + stile
    int b = blk >> 9, h = (blk >> 5) & 15, s0 = (blk & 31) * 64;
    int tid = threadIdx.x;
#pragma unroll
    for (int i = 0; i < 16; ++i) {
        int idx = tid + i * 256;
        int r = idx >> 6, d = idx & 63;
        tile[r][d] = v_tok[((size_t)(b * S_ + s0 + r)) * D_ + h * HD_ + d];
    }
    __syncthreads();
#pragma unroll
    for (int i = 0; i < 16; ++i) {
        int idx = tid + i * 256;
        int d = idx >> 6, cc = idx & 63;
        v_t[((size_t)((b * H_ + h) * HD_ + d)) * S_ + s0 + cc] =
            (unsigned short)f2bf(tile[cc][d]);
    }
}

// cpre[b,n,c] = mean_{j<32} rg[b, n*16+j, c]
__global__ void block_mean_kernel(const float* __restrict__ rg, float* __restrict__ cpre)
{
    int bn = blockIdx.x;
    int b = bn / NB_, n = bn % NB_;
    int s0 = n * 16;
    for (int c = threadIdx.x; c < D_; c += 256) {
        float sum = 0.f;
        for (int j = 0; j < 32; ++j)
            sum += rg[((size_t)b * S_ + s0 + j) * D_ + c];
        cpre[(size_t)bn * D_ + c] = sum * (1.f / 32.f);
    }
}

// q_mean_s[b,h,d] = mean_s q_tok[b,s,h*64+d]   (grid B*H, 256 threads)
__global__ void mean_qs_kernel(const float* __restrict__ q_tok, float* __restrict__ q_mean_s)
{
    int bh = blockIdx.x;
    int b = bh >> 4, h = bh & 15;
    int t = threadIdx.x, d = t & 63, sg = t >> 6;
    float sum = 0.f;
    for (int s = sg; s < S_; s += 4)
        sum += q_tok[((size_t)b * S_ + s) * D_ + (h << 6) + d];
    __shared__ float red[4][64];
    red[sg][d] = sum;
    __syncthreads();
    if (sg == 0)
        q_mean_s[bh * 64 + d] = (red[0][d] + red[1][d] + red[2][d] + red[3][d]) * (1.f / S_);
}

// q_mean_h[b,s,d] = mean_h q_tok[b,s,h*64+d]  (double) (grid B*S, 64 threads)
__global__ void mean_qh_kernel(const float* __restrict__ q_tok, double* __restrict__ q_mean_h)
{
    size_t bs = blockIdx.x;
    int d = threadIdx.x;
    double sum = 0.0;
    for (int h = 0; h < H_; ++h) sum += (double)q_tok[bs * D_ + h * 64 + d];
    q_mean_h[bs * 64 + d] = sum * (1.0 / H_);
}

// ckm[b,n,d] = mean_h cmp_k[b,n,h*64+d]  (double) (grid B*NB, 64 threads)
__global__ void mean_ckh_kernel(const float* __restrict__ cmp_k, double* __restrict__ ckm)
{
    size_t bn = blockIdx.x;
    int d = threadIdx.x;
    double sum = 0.0;
    for (int h = 0; h < H_; ++h) sum += (double)cmp_k[bn * D_ + h * 64 + d];
    ckm[bn * 64 + d] = sum * (1.0 / H_);
}

// out_cmp[b,h,:] = softmax(q_mean_s . cmp_k * SCALE) @ cmp_v   (grid B*H, 128 threads)
__launch_bounds__(128)
__global__ void out_cmp_kernel(const float* __restrict__ q_mean_s, const float* __restrict__ cmp_k,
                               const float* __restrict__ cmp_v, float* __restrict__ out_cmp)
{
    int bh = blockIdx.x;
    int b = bh >> 4, h = bh & 15;
    int t = threadIdx.x;
    __shared__ float qv[64];
    __shared__ float pv[128];
    __shared__ float red[128];
    if (t < 64) qv[t] = q_mean_s[bh * 64 + t];
    __syncthreads();
    float sc = -1e30f;
    if (t < NB_) {
        const float* kr = &cmp_k[((size_t)b * NB_ + t) * D_ + h * HD_];
        float sum = 0.f;
        for (int d = 0; d < 64; ++d) sum = fmaf(qv[d], kr[d], sum);
        sc = sum * SCALE_;
    }
    red[t] = sc;
    __syncthreads();
    for (int off = 64; off > 0; off >>= 1) {
        if (t < off) red[t] = fmaxf(red[t], red[t + off]);
        __syncthreads();
    }
    float mx = red[0];
    __syncthreads();
    float e = (t < NB_) ? __expf(sc - mx) : 0.f;
    pv[t] = e;
    red[t] = e;
    __syncthreads();
    for (int off = 64; off > 0; off >>= 1) {
        if (t < off) red[t] += red[t + off];
        __syncthreads();
    }
    float sm = red[0];
    __syncthreads();
    if (t < 64) {
        float o = 0.f;
        for (int n = 0; n < NB_; ++n)
            o = fmaf(pv[n], cmp_v[((size_t)b * NB_ + n) * D_ + h * HD_ + t], o);
        out_cmp[bh * 64 + t] = o / sm;
    }
}

// imp_all[b,n,s] = softmax_n(q_mean_h[b,s] . ckm[b,n] * SCALE)  fp64  (grid B*S, 128 thr)
__launch_bounds__(128)
__global__ void imp1_kernel(const double* __restrict__ q_mean_h, const double* __restrict__ ckm,
                            double* __restrict__ imp_all)
{
    int bs = blockIdx.x;
    int b = bs >> 11, s = bs & (S_ - 1);
    int t = threadIdx.x;
    __shared__ double qv[64];
    __shared__ double red[128];
    if (t < 64) qv[t] = q_mean_h[(size_t)bs * 64 + t];
    __syncthreads();
    double sc = -1e300;
    if (t < NB_) {
        const double* kr = &ckm[(b * NB_ + t) * 64];
        double sum = 0.0;
        for (int d = 0; d < 64; ++d) sum = fma(qv[d], kr[d], sum);
        sc = sum * (double)SCALE_;
    }
    red[t] = sc;
    __syncthreads();
    for (int off = 64; off > 0; off >>= 1) {
        if (t < off) red[t] = fmax(red[t], red[t + off]);
        __syncthreads();
    }
    double mx = red[0];
    __syncthreads();
    double e = (t < NB_) ? exp(sc - mx) : 0.0;
    red[t] = e;
    __syncthreads();
    for (int off = 64; off > 0; off >>= 1) {
        if (t < off) red[t] += red[t + off];
        __syncthreads();
    }
    double sm = red[0];
    if (t < NB_) imp_all[((size_t)(b * NB_ + t)) * S_ + s] = e / sm;
}

// imp[b,n] = mean_s imp_all[b,n,s]  fp64  (grid B*NB, 256 threads)
__global__ void imp2_kernel(const double* __restrict__ imp_all, double* __restrict__ imp)
{
    int bn = blockIdx.x;
    int t = threadIdx.x;
    double sum = 0.0;
    for (int s = t; s < S_; s += 256) sum += imp_all[(size_t)bn * S_ + s];
    __shared__ double red[256];
    red[t] = sum;
    __syncthreads();
    for (int off = 128; off > 0; off >>= 1) {
        if (t < off) red[t] += red[t + off];
        __syncthreads();
    }
    if (t == 0) imp[bn] = red[0] * (1.0 / S_);
}

// exact top-16 per batch, stable (lowest index wins ties) — matches jax.lax.top_k
__global__ void topk_kernel(const double* __restrict__ imp, int* __restrict__ topb)
{
    int b = threadIdx.x;
    if (b >= B_) return;
    unsigned long long used0 = 0ull, used1 = 0ull;
    for (int m = 0; m < NSEL_; ++m) {
        double best = -1e300;
        int bi = 0;
        for (int n = 0; n < NB_; ++n) {
            bool u = (n < 64) ? ((used0 >> n) & 1ull) : ((used1 >> (n - 64)) & 1ull);
            double v = imp[b * NB_ + n];
            if (!u && v > best) { best = v; bi = n; }
        }
        if (bi < 64) used0 |= 1ull << bi; else used1 |= 1ull << (bi - 64);
        topb[b * NSEL_ + m] = bi;
    }
}

// ---------------- MFMA flash attention ----------------
// One block = 4 waves; each wave owns 16 queries of one (b,h). Keys in chunks of 64.
// S^T = K·Q^T (C-layout: col=q=lane&15, row=key=(lane>>4)*4+reg) -> softmax stats
// need only shfl_xor 16/32, alpha is lane-uniform. P goes [q][key] bf16 to a
// per-wave LDS buffer (stride 72: 2-way bank alias = free), then O^T = V^T·P^T.
// MODE 0: window (last NCH*64 tokens). MODE 1: selected blocks; block>=32 is fully
// clamped to token S-1 (multiset semantics preserved).
template<int NCH, int MODE>
__launch_bounds__(256, 4)
__global__ void attn_mfma_kernel(const float* __restrict__ q_tok, const float* __restrict__ k_tok,
                                 const unsigned short* __restrict__ v_t,
                                 const int* __restrict__ topb, float* __restrict__ outp)
{
    __shared__ __attribute__((aligned(16))) char smem[27648];
    short* klds = (short*)smem;            // [64][72] bf16  (K: [key][d])
    short* vlds = (short*)(smem + 9216);   // [64][72] bf16  (V^T: [d][key])
    short* plds = (short*)(smem + 18432);  // per-wave [16][72] bf16 (P: [q][key])
    __shared__ int selb[NSEL_];
    const int tid = threadIdx.x;
    const int wid = tid >> 6, lane = tid & 63;
    const int lq = lane & 15, g = lane >> 4;
    const int blk = blockIdx.x;
    const int b = blk >> 9;
    const int h = (blk >> 5) & 15;
    const int q0 = (blk & 31) * 64 + wid * 16;
    short* pw = plds + wid * 16 * 72;

    if (MODE == 1 && tid < NSEL_) selb[tid] = topb[b * NSEL_ + tid];

    // Q fragments (B-operand of S^T): lane -> q=q0+lq, d = c32*32 + g*8 + j
    short8 qfrag[2];
    {
        const float* qp = q_tok + ((size_t)(b * S_ + q0 + lq)) * D_ + h * HD_ + g * 8;
#pragma unroll
        for (int c32 = 0; c32 < 2; ++c32) {
            f32x4 a = *(const f32x4*)(qp + c32 * 32);
            f32x4 bv = *(const f32x4*)(qp + c32 * 32 + 4);
            short8 f;
            f[0]=f2bf(a[0]); f[1]=f2bf(a[1]); f[2]=f2bf(a[2]); f[3]=f2bf(a[3]);
            f[4]=f2bf(bv[0]); f[5]=f2bf(bv[1]); f[6]=f2bf(bv[2]); f[7]=f2bf(bv[3]);
            qfrag[c32] = f;
        }
    }
    f32x4 oacc[4] = {};                 // O^T[d=m*16+g*4+reg][q=lq]
    float rm = -1e30f, rl = 0.f;

    for (int c = 0; c < NCH; ++c) {
        __syncthreads();                // prev chunk's LDS reads done (all waves)
        int t0;
        bool clamped = false;
        if (MODE == 0) t0 = S_ - NCH * 64 + c * 64;
        else { t0 = selb[c] * SELBLK_; clamped = (t0 >= S_); }
        // stage K (fp32->bf16) and V^T (bf16 row copy)
#pragma unroll
        for (int it = 0; it < 2; ++it) {
            int idx = tid + it * 256;
            int r = idx >> 3, cc = idx & 7;
            int tk = t0 + r; if (tk > S_ - 1) tk = S_ - 1;
            const float* kp = k_tok + ((size_t)(b * S_ + tk)) * D_ + h * HD_ + cc * 8;
            f32x4 a = *(const f32x4*)kp;
            f32x4 bv = *(const f32x4*)(kp + 4);
            short8 kf;
            kf[0]=f2bf(a[0]); kf[1]=f2bf(a[1]); kf[2]=f2bf(a[2]); kf[3]=f2bf(a[3]);
            kf[4]=f2bf(bv[0]); kf[5]=f2bf(bv[1]); kf[6]=f2bf(bv[2]); kf[7]=f2bf(bv[3]);
            *(short8*)(klds + r * 72 + cc * 8) = kf;
            const unsigned short* vrow = v_t + ((size_t)((b * H_ + h) * HD_ + r)) * S_;
            short8 vv;
            if (!clamped) {
                vv = *(const short8*)(vrow + t0 + cc * 8);
            } else {
                short x = (short)vrow[S_ - 1];
                vv = (short8){x, x, x, x, x, x, x, x};
            }
            *(short8*)(vlds + r * 72 + cc * 8) = vv;
        }
        __syncthreads();
        // S^T = K·Q^T
        f32x4 st[4];
#pragma unroll
        for (int sub = 0; sub < 4; ++sub) {
            short8 ka0 = *(const short8*)(klds + (sub * 16 + lq) * 72 + g * 8);
            short8 ka1 = *(const short8*)(klds + (sub * 16 + lq) * 72 + 32 + g * 8);
            f32x4 acc = {};
            acc = __builtin_amdgcn_mfma_f32_16x16x32_bf16(ka0, qfrag[0], acc, 0, 0, 0);
            acc = __builtin_amdgcn_mfma_f32_16x16x32_bf16(ka1, qfrag[1], acc, 0, 0, 0);
            st[sub] = acc;
        }
        // online softmax over this chunk's 64 keys (per query q=lq)
        float mx = -1e30f;
#pragma unroll
        for (int sub = 0; sub < 4; ++sub)
#pragma unroll
            for (int r = 0; r < 4; ++r) {
                st[sub][r] *= SCALE_;
                mx = fmaxf(mx, st[sub][r]);
            }
        mx = fmaxf(mx, __shfl_xor(mx, 16, 64));
        mx = fmaxf(mx, __shfl_xor(mx, 32, 64));
        float nm = fmaxf(rm, mx);
        float alpha = __expf(rm - nm);
        rm = nm;
        float ps = 0.f;
#pragma unroll
        for (int sub = 0; sub < 4; ++sub)
#pragma unroll
            for (int r = 0; r < 4; ++r) {
                float p = __expf(st[sub][r] - nm);
                st[sub][r] = p;
                ps += p;
            }
        ps += __shfl_xor(ps, 16, 64);
        ps += __shfl_xor(ps, 32, 64);
        rl = rl * alpha + ps;
#pragma unroll
        for (int m = 0; m < 4; ++m)
#pragma unroll
            for (int r = 0; r < 4; ++r) oacc[m][r] *= alpha;
        // P -> per-wave LDS [q][key] bf16 (no barrier: wave-private buffer)
#pragma unroll
        for (int sub = 0; sub < 4; ++sub)
#pragma unroll
            for (int r = 0; r < 4; ++r)
                pw[lq * 72 + sub * 16 + g * 4 + r] = f2bf(st[sub][r]);
        short8 pf0 = *(const short8*)(pw + lq * 72 + g * 8);
        short8 pf1 = *(const short8*)(pw + lq * 72 + 32 + g * 8);
        // O^T += V^T·P^T
#pragma unroll
        for (int m = 0; m < 4; ++m) {
            short8 va0 = *(const short8*)(vlds + (m * 16 + lq) * 72 + g * 8);
            short8 va1 = *(const short8*)(vlds + (m * 16 + lq) * 72 + 32 + g * 8);
            oacc[m] = __builtin_amdgcn_mfma_f32_16x16x32_bf16(va0, pf0, oacc[m], 0, 0, 0);
            oacc[m] = __builtin_amdgcn_mfma_f32_16x16x32_bf16(va1, pf1, oacc[m], 0, 0, 0);
        }
    }
    __syncthreads();                    // all waves done with klds/vlds
    // transpose O^T -> [q][d] via per-wave LDS, store coalesced fp32
    float invl = 1.f / rl;
    float* obuf = (float*)smem + wid * (16 * 68);
#pragma unroll
    for (int m = 0; m < 4; ++m)
#pragma unroll
        for (int r = 0; r < 4; ++r)
            obuf[lq * 68 + m * 16 + g * 4 + r] = oacc[m][r] * invl;
    {
        int q = lane >> 2, seg = lane & 3;
        const float* row = obuf + q * 68 + seg * 16;
        float* dst = outp + ((size_t)(b * S_ + q0 + q)) * D_ + h * HD_ + seg * 16;
#pragma unroll
        for (int k = 0; k < 4; ++k)
            *(f32x4*)(dst + k * 4) = *(const f32x4*)(row + k * 4);
    }
}

// gates = softmax([oc,osl,ow] @ w_g.T + b_g); out = g0*oc+g1*osl+g2*ow  (grid B*S, 128 thr)
__launch_bounds__(128)
__global__ void gate_kernel(const float* __restrict__ out_cmp, const float* __restrict__ o_slc,
                            const float* __restrict__ o_win, const float* __restrict__ w_g,
                            const float* __restrict__ b_g, float* __restrict__ outp)
{
    int bs = blockIdx.x;
    int b = bs >> 11;
    int t = threadIdx.x;
    float oc_r[8], os_r[8], ow_r[8];
    float g0 = 0.f, g1 = 0.f, g2 = 0.f;
#pragma unroll
    for (int i = 0; i < 8; ++i) {
        int c = t + i * 128;
        float oc = out_cmp[(b * H_ + (c >> 6)) * 64 + (c & 63)];
        float os = o_slc[(size_t)bs * D_ + c];
        float ow = o_win[(size_t)bs * D_ + c];
        oc_r[i] = oc; os_r[i] = os; ow_r[i] = ow;
        g0 += w_g[c] * oc + w_g[1024 + c] * os + w_g[2048 + c] * ow;
        g1 += w_g[3072 + c] * oc + w_g[3072 + 1024 + c] * os + w_g[3072 + 2048 + c] * ow;
        g2 += w_g[6144 + c] * oc + w_g[6144 + 1024 + c] * os + w_g[6144 + 2048 + c] * ow;
    }
    __shared__ float red[3][128];
    red[0][t] = g0; red[1][t] = g1; red[2][t] = g2;
    __syncthreads();
    for (int off = 64; off > 0; off >>= 1) {
        if (t < off) {
            red[0][t] += red[0][t + off];
            red[1][t] += red[1][t + off];
            red[2][t] += red[2][t + off];
        }
        __syncthreads();
    }
    float a0 = red[0][0] + b_g[0], a1 = red[1][0] + b_g[1], a2 = red[2][0] + b_g[2];
    float m = fmaxf(a0, fmaxf(a1, a2));
    float e0 = __expf(a0 - m), e1 = __expf(a1 - m), e2 = __expf(a2 - m);
    float inv = 1.f / (e0 + e1 + e2);
    e0 *= inv; e1 *= inv; e2 *= inv;
#pragma unroll
    for (int i = 0; i < 8; ++i) {
        int c = t + i * 128;
        outp[(size_t)bs * D_ + c] = e0 * oc_r[i] + e1 * os_r[i] + e2 * ow_r[i];
    }
}

extern "C" void kernel_launch(void* const* d_in, const int* in_sizes, int n_in,
                              void* d_out, int out_size, void* d_ws, size_t ws_size,
                              hipStream_t stream)
{
    const float* x     = (const float*)d_in[0];
    const float* pos   = (const float*)d_in[1];
    const float* w_qkv = (const float*)d_in[2];
    const float* b_qkv = (const float*)d_in[3];
    const float* w_c1  = (const float*)d_in[4];
    const float* b_c1  = (const float*)d_in[5];
    const float* w_c2  = (const float*)d_in[6];
    const float* b_c2  = (const float*)d_in[7];
    const float* w_g   = (const float*)d_in[8];
    const float* b_g   = (const float*)d_in[9];
    float* out = (float*)d_out;
    (void)in_sizes; (void)n_in; (void)out_size; (void)ws_size;

    char* wp = (char*)d_ws;
    size_t off = 0;
    auto alloc = [&](size_t nbytes) -> void* {
        void* p = (void*)(wp + off);
        off += ((nbytes + 255) / 256) * 256;
        return p;
    };
    const size_t NTOK = (size_t)B_ * S_ * D_;          // 8,388,608
    float* q_tok = (float*)alloc(NTOK * 4);
    float* k_tok = (float*)alloc(NTOK * 4);
    float* v_tok = (float*)alloc(NTOK * 4);
    float* o_slc = (float*)alloc(NTOK * 4);   // early life: rg (relu'd c1 output)
    float* o_win = (float*)alloc(NTOK * 4);   // early life: imp_all (fp64)
    float*  rg      = o_slc;
    double* imp_all = (double*)o_win;         // B*NB*S doubles = 8.3 MB < 32 MB
    unsigned short* v_t = (unsigned short*)alloc(NTOK * 2);  // bf16 V^T [b][h][d][s]
    float* cpre_k = (float*)alloc((size_t)B_ * NB_ * D_ * 4);
    float* cpre_v = (float*)alloc((size_t)B_ * NB_ * D_ * 4);
    float* cmp_k  = (float*)alloc((size_t)B_ * NB_ * D_ * 4);
    float* cmp_v  = (float*)alloc((size_t)B_ * NB_ * D_ * 4);
    float*  q_mean_s = (float*)alloc(B_ * H_ * 64 * 4);
    double* q_mean_h = (double*)alloc((size_t)B_ * S_ * 64 * 8);
    double* ckm  = (double*)alloc(B_ * NB_ * 64 * 8);
    float*  ocmp = (float*)alloc(B_ * H_ * 64 * 4);
    double* imp  = (double*)alloc(B_ * NB_ * 8);
    int*    topb = (int*)alloc(B_ * NSEL_ * 4);

    dim3 blk(256);
    // 1. QKV projection + scatter to head-major token layouts
    gemm_kernel<0, 2><<<dim3(128, 48), blk, 0, stream>>>(
        x, w_qkv, b_qkv, nullptr, S_ * B_, 3 * D_, D_, nullptr, q_tok, k_tok, v_tok);
    // 1b. bf16 V^T for the MFMA attention
    vt_kernel<<<2048, blk, 0, stream>>>(v_tok, v_t);
    // 2. compression: per-token c1+relu, block mean, c2
    gemm_kernel<1, 1><<<dim3(128, 16), blk, 0, stream>>>(
        k_tok, w_c1, b_c1, rg, B_ * S_, D_, D_ + 3, pos, nullptr, nullptr, nullptr);
    block_mean_kernel<<<B_ * NB_, blk, 0, stream>>>(rg, cpre_k);
    gemm_kernel<1, 1><<<dim3(128, 16), blk, 0, stream>>>(
        v_tok, w_c1, b_c1, rg, B_ * S_, D_, D_ + 3, pos, nullptr, nullptr, nullptr);
    block_mean_kernel<<<B_ * NB_, blk, 0, stream>>>(rg, cpre_v);
    gemm_kernel<0, 0><<<dim3(8, 16), blk, 0, stream>>>(
        cpre_k, w_c2, b_c2, cmp_k, B_ * NB_, D_, D_, nullptr, nullptr, nullptr, nullptr);
    gemm_kernel<0, 0><<<dim3(8, 16), blk, 0, stream>>>(
        cpre_v, w_c2, b_c2, cmp_v, B_ * NB_, D_, D_, nullptr, nullptr, nullptr, nullptr);
    // 3. means
    mean_qs_kernel<<<B_ * H_, blk, 0, stream>>>(q_tok, q_mean_s);
    mean_qh_kernel<<<B_ * S_, 64, 0, stream>>>(q_tok, q_mean_h);
    mean_ckh_kernel<<<B_ * NB_, 64, 0, stream>>>(cmp_k, ckm);
    // 4. compressed-branch attention + importance (fp64) + top-k
    out_cmp_kernel<<<B_ * H_, 128, 0, stream>>>(q_mean_s, cmp_k, cmp_v, ocmp);
    imp1_kernel<<<B_ * S_, 128, 0, stream>>>(q_mean_h, ckm, imp_all);
    imp2_kernel<<<B_ * NB_, 256, 0, stream>>>(imp_all, imp);
    topk_kernel<<<1, 64, 0, stream>>>(imp, topb);
    // 5. selected + window attention (MFMA flash)
    attn_mfma_kernel<16, 1><<<2048, blk, 0, stream>>>(q_tok, k_tok, v_t, topb, o_slc);
    attn_mfma_kernel<8, 0><<<2048, blk, 0, stream>>>(q_tok, k_tok, v_t, nullptr, o_win);
    // 6. gate + combine
    gate_kernel<<<B_ * S_, 128, 0, stream>>>(ocmp, o_slc, o_win, w_g, b_g, out);
}

// Round 4
// 920.947 us; speedup vs baseline: 6.0801x; 2.6550x over previous
//
#include <hip/hip_runtime.h>
#include <hip/hip_bf16.h>
#include <math.h>

#define S_ 2048
#define B_ 4
#define D_ 1024
#define H_ 16
#define HD_ 64
#define NB_ 127
#define WIN_ 512
#define NSEL_ 16
#define SELBLK_ 64
#define SCALE_ 0.125f

typedef __attribute__((ext_vector_type(8))) short short8;
typedef __attribute__((ext_vector_type(4))) float f32x4;
typedef unsigned short u16;

__device__ inline float bf2f(u16 u) {
    union { unsigned int i; float f; } c; c.i = ((unsigned int)u) << 16; return c.f;
}
__device__ inline u16 f2bf_u(float f) {
    __hip_bfloat16 h = __float2bfloat16(f);
    return *reinterpret_cast<u16*>(&h);
}

// ---------- split fp32 -> bf16 hi/lo (flat, n4 = n/4 float4 groups) ----------
__global__ void split_kernel(const float* __restrict__ src, u16* __restrict__ hi,
                             u16* __restrict__ lo, int n4)
{
    int i = blockIdx.x * 256 + threadIdx.x;
    if (i >= n4) return;
    f32x4 v = ((const f32x4*)src)[i];
    ushort4 h, l;
    u16 h0 = f2bf_u(v[0]), h1 = f2bf_u(v[1]), h2 = f2bf_u(v[2]), h3 = f2bf_u(v[3]);
    h.x = h0; h.y = h1; h.z = h2; h.w = h3;
    ((ushort4*)hi)[i] = h;
    if (lo) {
        l.x = f2bf_u(v[0] - bf2f(h0)); l.y = f2bf_u(v[1] - bf2f(h1));
        l.z = f2bf_u(v[2] - bf2f(h2)); l.w = f2bf_u(v[3] - bf2f(h3));
        ((ushort4*)lo)[i] = l;
    }
}

// ---------- permute w_qkv rows to [q|k|v] grouping + split + bias permute ----------
__global__ void wqkv_prep_kernel(const float* __restrict__ wqkv, const float* __restrict__ bqkv,
                                 u16* __restrict__ whi, u16* __restrict__ wlo,
                                 float* __restrict__ bperm)
{
    int n = blockIdx.x;                  // 0..3071 output row
    int grp = n >> 10, wd = n & 1023, h = wd >> 6, d = wd & 63;
    int src = h * 192 + grp * 64 + d;
    const float* srow = wqkv + (size_t)src * 1024;
    int c = threadIdx.x * 4;
    f32x4 v = *(const f32x4*)(srow + c);
    size_t o = (size_t)n * 1024 + c;
#pragma unroll
    for (int j = 0; j < 4; ++j) {
        u16 hb = f2bf_u(v[j]);
        whi[o + j] = hb;
        wlo[o + j] = f2bf_u(v[j] - bf2f(hb));
    }
    if (threadIdx.x == 0) bperm[n] = bqkv[src];
}

// ---------- split w_c1 (1024 x 1027 fp32) -> 1024 x 1032 bf16 hi/lo (K cols only) ----------
__global__ void w1_split_kernel(const float* __restrict__ w1, u16* __restrict__ hi,
                                u16* __restrict__ lo)
{
    int n = blockIdx.x;
    const float* srow = w1 + (size_t)n * 1027;
    int c = threadIdx.x * 4;
    size_t o = (size_t)n * 1032 + c;
#pragma unroll
    for (int j = 0; j < 4; ++j) {
        float x = srow[c + j];
        u16 hb = f2bf_u(x);
        hi[o + j] = hb;
        lo[o + j] = f2bf_u(x - bf2f(hb));
    }
}

// ---------------- split-bf16 MFMA GEMM: C = A @ B^T (+bias, epilogues) ----------------
// A: M x K bf16 hi/lo (lda), B: N x K bf16 hi/lo (ldb). 128x128 tile, BK=32.
// NPASS: 3 = AhBh+AlBh+AhBl (fp32-class), 1 = AhBh (bf16-class).
// EPI 0: qkv scatter -> Oh/Ol bf16 at ((b*S+s)*D+gn), gm=s*4+b. WLO: also write lo.
// EPI 1: c1: v += bias + dot3(pos[s],w1f[gn,1024:1027]); relu; Cf[gm*1024+gn]. gm=b*S+s.
// EPI 2: plain: Cf[gm*1024+gn] = v+bias (guard gm<M).
template<int NPASS, int EPI, bool WLO>
__launch_bounds__(256, 2)
__global__ void mgemm_kernel(const u16* __restrict__ Ah, const u16* __restrict__ Al,
                             const u16* __restrict__ Bh, const u16* __restrict__ Bl,
                             int M, int K, int lda, int ldb,
                             const float* __restrict__ bias,
                             float* __restrict__ Cf,
                             u16* __restrict__ Oh, u16* __restrict__ Ol,
                             const float* __restrict__ pos, const float* __restrict__ w1f)
{
    constexpr int NBUF = (NPASS == 3) ? 4 : 2;
    __shared__ u16 lds[NBUF * 4096];     // per buffer: 128 rows * 4 slots * 8 shorts
    u16* ldsAh = lds;
    u16* ldsBh = lds + 4096;
    const int tid = threadIdx.x;
    const int w = tid >> 6, lane = tid & 63;
    const int lq = lane & 15, g = lane >> 4;
    const int wm = (w & 1) * 64, wn = (w >> 1) * 64;
    const int bm = blockIdx.x * 128, bn = blockIdx.y * 128;
    const int i4 = lane >> 2;                          // row within 16-group
    const int kc = (lane & 3) ^ ((lane >> 3) & 3);     // xor-swizzled k-chunk
    f32x4 acc[4][4] = {};

    const u16* gA = Ah + (size_t)(bm + w * 32 + i4) * lda + kc * 8;
    const u16* gB = Bh + (size_t)(bn + w * 32 + i4) * ldb + kc * 8;
    const u16* gAl = nullptr; const u16* gBl = nullptr;
    u16* ldsAl = nullptr; u16* ldsBl = nullptr;
    if (NPASS == 3) {
        gAl = Al + (size_t)(bm + w * 32 + i4) * lda + kc * 8;
        gBl = Bl + (size_t)(bn + w * 32 + i4) * ldb + kc * 8;
        ldsAl = lds + 8192;
        ldsBl = lds + 12288;
    }
    const int sbase = w * 1024 + lane * 8;             // half0 slot offset (shorts)

    for (int k0 = 0; k0 < K; k0 += 32) {
        __syncthreads();
        short8 a0 = *(const short8*)(gA + k0);
        short8 a1 = *(const short8*)(gA + 16 * lda + k0);
        short8 b0 = *(const short8*)(gB + k0);
        short8 b1 = *(const short8*)(gB + 16 * ldb + k0);
        short8 al0, al1, bl0, bl1;
        if (NPASS == 3) {
            al0 = *(const short8*)(gAl + k0);
            al1 = *(const short8*)(gAl + 16 * lda + k0);
            bl0 = *(const short8*)(gBl + k0);
            bl1 = *(const short8*)(gBl + 16 * ldb + k0);
        }
        *(short8*)(ldsAh + sbase) = a0;
        *(short8*)(ldsAh + sbase + 512) = a1;
        *(short8*)(ldsBh + sbase) = b0;
        *(short8*)(ldsBh + sbase + 512) = b1;
        if (NPASS == 3) {
            *(short8*)(ldsAl + sbase) = al0;
            *(short8*)(ldsAl + sbase + 512) = al1;
            *(short8*)(ldsBl + sbase) = bl0;
            *(short8*)(ldsBl + sbase + 512) = bl1;
        }
        __syncthreads();
        short8 fa[4], fal[4];
#pragma unroll
        for (int i = 0; i < 4; ++i) {
            int row = wm + i * 16 + lq;
            int sl = row * 4 + (g ^ ((row >> 1) & 3));
            fa[i] = *(const short8*)(ldsAh + sl * 8);
            if (NPASS == 3) fal[i] = *(const short8*)(ldsAl + sl * 8);
        }
#pragma unroll
        for (int jb = 0; jb < 4; ++jb) {
            int row = wn + jb * 16 + lq;
            int sl = row * 4 + (g ^ ((row >> 1) & 3));
            short8 fb = *(const short8*)(ldsBh + sl * 8);
            short8 fbl;
            if (NPASS == 3) fbl = *(const short8*)(ldsBl + sl * 8);
#pragma unroll
            for (int i = 0; i < 4; ++i) {
                acc[i][jb] = __builtin_amdgcn_mfma_f32_16x16x32_bf16(fa[i], fb, acc[i][jb], 0, 0, 0);
                if (NPASS == 3) {
                    acc[i][jb] = __builtin_amdgcn_mfma_f32_16x16x32_bf16(fal[i], fb, acc[i][jb], 0, 0, 0);
                    acc[i][jb] = __builtin_amdgcn_mfma_f32_16x16x32_bf16(fa[i], fbl, acc[i][jb], 0, 0, 0);
                }
            }
        }
    }
    // epilogue: C element (row = wm+i*16+g*4+r, col = wn+jb*16+lq)
#pragma unroll
    for (int i = 0; i < 4; ++i) {
#pragma unroll
        for (int jb = 0; jb < 4; ++jb) {
#pragma unroll
            for (int r = 0; r < 4; ++r) {
                int gm = bm + wm + i * 16 + g * 4 + r;
                int gn = bn + wn + jb * 16 + lq;
                float v = acc[i][jb][r] + bias[gn];
                if (EPI == 0) {
                    int s = gm >> 2, bb = gm & 3;
                    size_t idx = ((size_t)(bb * S_ + s)) * D_ + gn;
                    u16 hb = f2bf_u(v);
                    Oh[idx] = hb;
                    if (WLO) Ol[idx] = f2bf_u(v - bf2f(hb));
                } else if (EPI == 1) {
                    int st = gm & (S_ - 1);
                    v += pos[st * 3 + 0] * w1f[(size_t)gn * 1027 + 1024]
                       + pos[st * 3 + 1] * w1f[(size_t)gn * 1027 + 1025]
                       + pos[st * 3 + 2] * w1f[(size_t)gn * 1027 + 1026];
                    Cf[(size_t)gm * 1024 + gn] = fmaxf(v, 0.f);
                } else {
                    if (gm < M) Cf[(size_t)gm * 1024 + gn] = v;
                }
            }
        }
    }
}

// v_t[b][h][d][s] = transpose of v_hi[b][s][h*64+d] (bf16 -> bf16)
__launch_bounds__(256)
__global__ void vt_kernel(const u16* __restrict__ v_hi, u16* __restrict__ v_t)
{
    __shared__ u16 tile[64][68];
    int blk = blockIdx.x;                 // b*512 + h*32 + stile
    int b = blk >> 9, h = (blk >> 5) & 15, s0 = (blk & 31) * 64;
    int tid = threadIdx.x;
#pragma unroll
    for (int i = 0; i < 16; ++i) {
        int idx = tid + i * 256;
        int r = idx >> 6, d = idx & 63;
        tile[r][d] = v_hi[((size_t)(b * S_ + s0 + r)) * D_ + h * HD_ + d];
    }
    __syncthreads();
#pragma unroll
    for (int i = 0; i < 16; ++i) {
        int idx = tid + i * 256;
        int d = idx >> 6, cc = idx & 63;
        v_t[((size_t)((b * H_ + h) * HD_ + d)) * S_ + s0 + cc] = tile[cc][d];
    }
}

// cpre[b,n,c] = mean_{j<32} rg[b, n*16+j, c]
__global__ void block_mean_kernel(const float* __restrict__ rg, float* __restrict__ cpre)
{
    int bn = blockIdx.x;
    int b = bn / NB_, n = bn % NB_;
    int s0 = n * 16;
    for (int c = threadIdx.x; c < D_; c += 256) {
        float sum = 0.f;
        for (int j = 0; j < 32; ++j)
            sum += rg[((size_t)b * S_ + s0 + j) * D_ + c];
        cpre[(size_t)bn * D_ + c] = sum * (1.f / 32.f);
    }
}

// q_mean_s[b,h,d] = mean_s q[b,s,h*64+d]  (from q_hi)
__global__ void mean_qs_kernel(const u16* __restrict__ q_hi, float* __restrict__ q_mean_s)
{
    int bh = blockIdx.x;
    int b = bh >> 4, h = bh & 15;
    int t = threadIdx.x, d = t & 63, sg = t >> 6;
    float sum = 0.f;
    for (int s = sg; s < S_; s += 4)
        sum += bf2f(q_hi[((size_t)b * S_ + s) * D_ + (h << 6) + d]);
    __shared__ float red[4][64];
    red[sg][d] = sum;
    __syncthreads();
    if (sg == 0)
        q_mean_s[bh * 64 + d] = (red[0][d] + red[1][d] + red[2][d] + red[3][d]) * (1.f / S_);
}

// q_mean_h[b,s,d] = mean_h (q_hi+q_lo)  (double)
__global__ void mean_qh_kernel(const u16* __restrict__ q_hi, const u16* __restrict__ q_lo,
                               double* __restrict__ q_mean_h)
{
    size_t bs = blockIdx.x;
    int d = threadIdx.x;
    double sum = 0.0;
    for (int h = 0; h < H_; ++h) {
        size_t idx = bs * D_ + h * 64 + d;
        sum += (double)bf2f(q_hi[idx]) + (double)bf2f(q_lo[idx]);
    }
    q_mean_h[bs * 64 + d] = sum * (1.0 / H_);
}

// ckm[b,n,d] = mean_h cmp_k[b,n,h*64+d]  (double)
__global__ void mean_ckh_kernel(const float* __restrict__ cmp_k, double* __restrict__ ckm)
{
    size_t bn = blockIdx.x;
    int d = threadIdx.x;
    double sum = 0.0;
    for (int h = 0; h < H_; ++h) sum += (double)cmp_k[bn * D_ + h * 64 + d];
    ckm[bn * 64 + d] = sum * (1.0 / H_);
}

// out_cmp[b,h,:] = softmax(q_mean_s . cmp_k * SCALE) @ cmp_v
__launch_bounds__(128)
__global__ void out_cmp_kernel(const float* __restrict__ q_mean_s, const float* __restrict__ cmp_k,
                               const float* __restrict__ cmp_v, float* __restrict__ out_cmp)
{
    int bh = blockIdx.x;
    int b = bh >> 4, h = bh & 15;
    int t = threadIdx.x;
    __shared__ float qv[64];
    __shared__ float pv[128];
    __shared__ float red[128];
    if (t < 64) qv[t] = q_mean_s[bh * 64 + t];
    __syncthreads();
    float sc = -1e30f;
    if (t < NB_) {
        const float* kr = &cmp_k[((size_t)b * NB_ + t) * D_ + h * HD_];
        float sum = 0.f;
        for (int d = 0; d < 64; ++d) sum = fmaf(qv[d], kr[d], sum);
        sc = sum * SCALE_;
    }
    red[t] = sc;
    __syncthreads();
    for (int off = 64; off > 0; off >>= 1) {
        if (t < off) red[t] = fmaxf(red[t], red[t + off]);
        __syncthreads();
    }
    float mx = red[0];
    __syncthreads();
    float e = (t < NB_) ? __expf(sc - mx) : 0.f;
    pv[t] = e;
    red[t] = e;
    __syncthreads();
    for (int off = 64; off > 0; off >>= 1) {
        if (t < off) red[t] += red[t + off];
        __syncthreads();
    }
    float sm = red[0];
    __syncthreads();
    if (t < 64) {
        float o = 0.f;
        for (int n = 0; n < NB_; ++n)
            o = fmaf(pv[n], cmp_v[((size_t)b * NB_ + n) * D_ + h * HD_ + t], o);
        out_cmp[bh * 64 + t] = o / sm;
    }
}

// imp_all[b,n,s] = softmax_n(q_mean_h[b,s] . ckm[b,n] * SCALE)  fp64
__launch_bounds__(128)
__global__ void imp1_kernel(const double* __restrict__ q_mean_h, const double* __restrict__ ckm,
                            double* __restrict__ imp_all)
{
    int bs = blockIdx.x;
    int b = bs >> 11, s = bs & (S_ - 1);
    int t = threadIdx.x;
    __shared__ double qv[64];
    __shared__ double red[128];
    if (t < 64) qv[t] = q_mean_h[(size_t)bs * 64 + t];
    __syncthreads();
    double sc = -1e300;
    if (t < NB_) {
        const double* kr = &ckm[(b * NB_ + t) * 64];
        double sum = 0.0;
        for (int d = 0; d < 64; ++d) sum = fma(qv[d], kr[d], sum);
        sc = sum * (double)SCALE_;
    }
    red[t] = sc;
    __syncthreads();
    for (int off = 64; off > 0; off >>= 1) {
        if (t < off) red[t] = fmax(red[t], red[t + off]);
        __syncthreads();
    }
    double mx = red[0];
    __syncthreads();
    double e = (t < NB_) ? exp(sc - mx) : 0.0;
    red[t] = e;
    __syncthreads();
    for (int off = 64; off > 0; off >>= 1) {
        if (t < off) red[t] += red[t + off];
        __syncthreads();
    }
    double sm = red[0];
    if (t < NB_) imp_all[((size_t)(b * NB_ + t)) * S_ + s] = e / sm;
}

// imp[b,n] = mean_s imp_all[b,n,s]  fp64
__global__ void imp2_kernel(const double* __restrict__ imp_all, double* __restrict__ imp)
{
    int bn = blockIdx.x;
    int t = threadIdx.x;
    double sum = 0.0;
    for (int s = t; s < S_; s += 256) sum += imp_all[(size_t)bn * S_ + s];
    __shared__ double red[256];
    red[t] = sum;
    __syncthreads();
    for (int off = 128; off > 0; off >>= 1) {
        if (t < off) red[t] += red[t + off];
        __syncthreads();
    }
    if (t == 0) imp[bn] = red[0] * (1.0 / S_);
}

// exact top-16 per batch, stable (lowest index wins ties)
__global__ void topk_kernel(const double* __restrict__ imp, int* __restrict__ topb)
{
    int b = threadIdx.x;
    if (b >= B_) return;
    unsigned long long used0 = 0ull, used1 = 0ull;
    for (int m = 0; m < NSEL_; ++m) {
        double best = -1e300;
        int bi = 0;
        for (int n = 0; n < NB_; ++n) {
            bool u = (n < 64) ? ((used0 >> n) & 1ull) : ((used1 >> (n - 64)) & 1ull);
            double v = imp[b * NB_ + n];
            if (!u && v > best) { best = v; bi = n; }
        }
        if (bi < 64) used0 |= 1ull << bi; else used1 |= 1ull << (bi - 64);
        topb[b * NSEL_ + m] = bi;
    }
}

// ---------------- MFMA flash attention (bf16 inputs) ----------------
template<int NCH, int MODE>
__launch_bounds__(256, 4)
__global__ void attn_mfma_kernel(const u16* __restrict__ q_hi, const u16* __restrict__ k_hi,
                                 const u16* __restrict__ v_t,
                                 const int* __restrict__ topb, float* __restrict__ outp)
{
    __shared__ __attribute__((aligned(16))) char smem[27648];
    u16* klds = (u16*)smem;            // [64][72] bf16  (K: [key][d])
    u16* vlds = (u16*)(smem + 9216);   // [64][72] bf16  (V^T: [d][key])
    u16* plds = (u16*)(smem + 18432);  // per-wave [16][72] bf16 (P: [q][key])
    __shared__ int selb[NSEL_];
    const int tid = threadIdx.x;
    const int wid = tid >> 6, lane = tid & 63;
    const int lq = lane & 15, g = lane >> 4;
    const int blk = blockIdx.x;
    const int b = blk >> 9;
    const int h = (blk >> 5) & 15;
    const int q0 = (blk & 31) * 64 + wid * 16;
    u16* pw = plds + wid * 16 * 72;

    if (MODE == 1 && tid < NSEL_) selb[tid] = topb[b * NSEL_ + tid];

    short8 qfrag[2];
    {
        const u16* qp = q_hi + ((size_t)(b * S_ + q0 + lq)) * D_ + h * HD_ + g * 8;
        qfrag[0] = *(const short8*)qp;
        qfrag[1] = *(const short8*)(qp + 32);
    }
    f32x4 oacc[4] = {};
    float rm = -1e30f, rl = 0.f;

    for (int c = 0; c < NCH; ++c) {
        __syncthreads();
        int t0;
        bool clamped = false;
        if (MODE == 0) t0 = S_ - NCH * 64 + c * 64;
        else { t0 = selb[c] * SELBLK_; clamped = (t0 >= S_); }
#pragma unroll
        for (int it = 0; it < 2; ++it) {
            int idx = tid + it * 256;
            int r = idx >> 3, cc = idx & 7;
            int tk = t0 + r; if (tk > S_ - 1) tk = S_ - 1;
            *(short8*)(klds + r * 72 + cc * 8) =
                *(const short8*)(k_hi + ((size_t)(b * S_ + tk)) * D_ + h * HD_ + cc * 8);
            const u16* vrow = v_t + ((size_t)((b * H_ + h) * HD_ + r)) * S_;
            short8 vv;
            if (!clamped) {
                vv = *(const short8*)(vrow + t0 + cc * 8);
            } else {
                short x = (short)vrow[S_ - 1];
                vv = (short8){x, x, x, x, x, x, x, x};
            }
            *(short8*)(vlds + r * 72 + cc * 8) = vv;
        }
        __syncthreads();
        f32x4 st[4];
#pragma unroll
        for (int sub = 0; sub < 4; ++sub) {
            short8 ka0 = *(const short8*)(klds + (sub * 16 + lq) * 72 + g * 8);
            short8 ka1 = *(const short8*)(klds + (sub * 16 + lq) * 72 + 32 + g * 8);
            f32x4 acc = {};
            acc = __builtin_amdgcn_mfma_f32_16x16x32_bf16(ka0, qfrag[0], acc, 0, 0, 0);
            acc = __builtin_amdgcn_mfma_f32_16x16x32_bf16(ka1, qfrag[1], acc, 0, 0, 0);
            st[sub] = acc;
        }
        float mx = -1e30f;
#pragma unroll
        for (int sub = 0; sub < 4; ++sub)
#pragma unroll
            for (int r = 0; r < 4; ++r) {
                st[sub][r] *= SCALE_;
                mx = fmaxf(mx, st[sub][r]);
            }
        mx = fmaxf(mx, __shfl_xor(mx, 16, 64));
        mx = fmaxf(mx, __shfl_xor(mx, 32, 64));
        float nm = fmaxf(rm, mx);
        float alpha = __expf(rm - nm);
        rm = nm;
        float ps = 0.f;
#pragma unroll
        for (int sub = 0; sub < 4; ++sub)
#pragma unroll
            for (int r = 0; r < 4; ++r) {
                float p = __expf(st[sub][r] - nm);
                st[sub][r] = p;
                ps += p;
            }
        ps += __shfl_xor(ps, 16, 64);
        ps += __shfl_xor(ps, 32, 64);
        rl = rl * alpha + ps;
#pragma unroll
        for (int m = 0; m < 4; ++m)
#pragma unroll
            for (int r = 0; r < 4; ++r) oacc[m][r] *= alpha;
#pragma unroll
        for (int sub = 0; sub < 4; ++sub)
#pragma unroll
            for (int r = 0; r < 4; ++r)
                pw[lq * 72 + sub * 16 + g * 4 + r] = f2bf_u(st[sub][r]);
        short8 pf0 = *(const short8*)(pw + lq * 72 + g * 8);
        short8 pf1 = *(const short8*)(pw + lq * 72 + 32 + g * 8);
#pragma unroll
        for (int m = 0; m < 4; ++m) {
            short8 va0 = *(const short8*)(vlds + (m * 16 + lq) * 72 + g * 8);
            short8 va1 = *(const short8*)(vlds + (m * 16 + lq) * 72 + 32 + g * 8);
            oacc[m] = __builtin_amdgcn_mfma_f32_16x16x32_bf16(va0, pf0, oacc[m], 0, 0, 0);
            oacc[m] = __builtin_amdgcn_mfma_f32_16x16x32_bf16(va1, pf1, oacc[m], 0, 0, 0);
        }
    }
    __syncthreads();
    float invl = 1.f / rl;
    float* obuf = (float*)smem + wid * (16 * 68);
#pragma unroll
    for (int m = 0; m < 4; ++m)
#pragma unroll
        for (int r = 0; r < 4; ++r)
            obuf[lq * 68 + m * 16 + g * 4 + r] = oacc[m][r] * invl;
    {
        int q = lane >> 2, seg = lane & 3;
        const float* row = obuf + q * 68 + seg * 16;
        float* dst = outp + ((size_t)(b * S_ + q0 + q)) * D_ + h * HD_ + seg * 16;
#pragma unroll
        for (int k = 0; k < 4; ++k)
            *(f32x4*)(dst + k * 4) = *(const f32x4*)(row + k * 4);
    }
}

// gates = softmax([oc,osl,ow] @ w_g.T + b_g); out = g0*oc+g1*osl+g2*ow
__launch_bounds__(128)
__global__ void gate_kernel(const float* __restrict__ out_cmp, const float* __restrict__ o_slc,
                            const float* __restrict__ o_win, const float* __restrict__ w_g,
                            const float* __restrict__ b_g, float* __restrict__ outp)
{
    int bs = blockIdx.x;
    int b = bs >> 11;
    int t = threadIdx.x;
    float oc_r[8], os_r[8], ow_r[8];
    float g0 = 0.f, g1 = 0.f, g2 = 0.f;
#pragma unroll
    for (int i = 0; i < 8; ++i) {
        int c = t + i * 128;
        float oc = out_cmp[(b * H_ + (c >> 6)) * 64 + (c & 63)];
        float os = o_slc[(size_t)bs * D_ + c];
        float ow = o_win[(size_t)bs * D_ + c];
        oc_r[i] = oc; os_r[i] = os; ow_r[i] = ow;
        g0 += w_g[c] * oc + w_g[1024 + c] * os + w_g[2048 + c] * ow;
        g1 += w_g[3072 + c] * oc + w_g[3072 + 1024 + c] * os + w_g[3072 + 2048 + c] * ow;
        g2 += w_g[6144 + c] * oc + w_g[6144 + 1024 + c] * os + w_g[6144 + 2048 + c] * ow;
    }
    __shared__ float red[3][128];
    red[0][t] = g0; red[1][t] = g1; red[2][t] = g2;
    __syncthreads();
    for (int off = 64; off > 0; off >>= 1) {
        if (t < off) {
            red[0][t] += red[0][t + off];
            red[1][t] += red[1][t + off];
            red[2][t] += red[2][t + off];
        }
        __syncthreads();
    }
    float a0 = red[0][0] + b_g[0], a1 = red[1][0] + b_g[1], a2 = red[2][0] + b_g[2];
    float m = fmaxf(a0, fmaxf(a1, a2));
    float e0 = __expf(a0 - m), e1 = __expf(a1 - m), e2 = __expf(a2 - m);
    float inv = 1.f / (e0 + e1 + e2);
    e0 *= inv; e1 *= inv; e2 *= inv;
#pragma unroll
    for (int i = 0; i < 8; ++i) {
        int c = t + i * 128;
        outp[(size_t)bs * D_ + c] = e0 * oc_r[i] + e1 * os_r[i] + e2 * ow_r[i];
    }
}

extern "C" void kernel_launch(void* const* d_in, const int* in_sizes, int n_in,
                              void* d_out, int out_size, void* d_ws, size_t ws_size,
                              hipStream_t stream)
{
    const float* x     = (const float*)d_in[0];
    const float* pos   = (const float*)d_in[1];
    const float* w_qkv = (const float*)d_in[2];
    const float* b_qkv = (const float*)d_in[3];
    const float* w_c1  = (const float*)d_in[4];
    const float* b_c1  = (const float*)d_in[5];
    const float* w_c2  = (const float*)d_in[6];
    const float* b_c2  = (const float*)d_in[7];
    const float* w_g   = (const float*)d_in[8];
    const float* b_g   = (const float*)d_in[9];
    float* out = (float*)d_out;
    (void)in_sizes; (void)n_in; (void)out_size; (void)ws_size;

    char* wp = (char*)d_ws;
    size_t off = 0;
    auto alloc = [&](size_t nbytes) -> void* {
        void* p = (void*)(wp + off);
        off += ((nbytes + 255) / 256) * 256;
        return p;
    };
    const size_t NTOK = (size_t)B_ * S_ * D_;          // 8,388,608
    float* o_slc = (float*)alloc(NTOK * 4);            // early life: rg
    float* o_win = (float*)alloc(NTOK * 4);            // early life: imp_all (fp64)
    float*  rg      = o_slc;
    double* imp_all = (double*)o_win;
    u16* q_hi = (u16*)alloc(NTOK * 2);
    u16* q_lo = (u16*)alloc(NTOK * 2);
    u16* k_hi = (u16*)alloc(NTOK * 2);
    u16* k_lo = (u16*)alloc(NTOK * 2);
    u16* v_hi = (u16*)alloc(NTOK * 2);
    u16* x_hi = (u16*)alloc(NTOK * 2);                 // late life: v_t
    u16* v_t  = x_hi;                                  // alias (x_hi dead after QKV-v)
    u16* x_lo = (u16*)alloc(NTOK * 2);                 // late life: misc region
    // misc sub-allocator inside x_lo (all used only after QKV-k completes)
    {
    }
    char* mp = (char*)x_lo;
    size_t moff = 0;
    auto malloc2 = [&](size_t nbytes) -> void* {
        void* p = (void*)(mp + moff);
        moff += ((nbytes + 255) / 256) * 256;
        return p;
    };
    const size_t NCMP = (size_t)B_ * NB_ * D_;         // 520,192
    float* cpre_k = (float*)malloc2(NCMP * 4);
    float* cpre_v = (float*)malloc2(NCMP * 4);
    float* cmp_k  = (float*)malloc2(NCMP * 4);
    float* cmp_v  = (float*)malloc2(NCMP * 4);
    u16* cpk_hi = (u16*)malloc2(NCMP * 2);
    u16* cpk_lo = (u16*)malloc2(NCMP * 2);
    u16* cpv_hi = (u16*)malloc2(NCMP * 2);
    float*  q_mean_s = (float*)malloc2(B_ * H_ * 64 * 4);
    double* ckm  = (double*)malloc2(B_ * NB_ * 64 * 8);
    float*  ocmp = (float*)malloc2(B_ * H_ * 64 * 4);
    double* imp  = (double*)malloc2(B_ * NB_ * 8);
    int*    topb = (int*)malloc2(B_ * NSEL_ * 4);
    malloc2(65536);                                    // overread guard pad
    // weights (live across the whole GEMM phase)
    u16* wq_hi = (u16*)alloc((size_t)3072 * 1024 * 2);
    u16* wq_lo = (u16*)alloc((size_t)3072 * 1024 * 2);
    float* b_perm = (float*)alloc(3072 * 4);
    u16* w1h = (u16*)alloc((size_t)1024 * 1032 * 2);
    u16* w1l = (u16*)alloc((size_t)1024 * 1032 * 2);
    u16* w2h = (u16*)alloc((size_t)1024 * 1024 * 2);
    u16* w2l = (u16*)alloc((size_t)1024 * 1024 * 2);
    double* q_mean_h = (double*)alloc((size_t)B_ * S_ * 64 * 8);
    alloc(65536);                                      // tail pad

    dim3 blk(256);
    // 0. splits
    split_kernel<<<(int)(NTOK / 1024), blk, 0, stream>>>(x, x_hi, x_lo, (int)(NTOK / 4));
    wqkv_prep_kernel<<<3072, blk, 0, stream>>>(w_qkv, b_qkv, wq_hi, wq_lo, b_perm);
    w1_split_kernel<<<1024, blk, 0, stream>>>(w_c1, w1h, w1l);
    split_kernel<<<1024, blk, 0, stream>>>(w_c2, w2h, w2l, 1024 * 1024 / 4);
    // 1. QKV projection (q,k: x3 split-accurate; v: x1)
    mgemm_kernel<3, 0, true><<<dim3(64, 8), blk, 0, stream>>>(
        x_hi, x_lo, wq_hi, wq_lo, S_ * B_, 1024, 1024, 1024,
        b_perm, nullptr, q_hi, q_lo, nullptr, nullptr);
    mgemm_kernel<3, 0, true><<<dim3(64, 8), blk, 0, stream>>>(
        x_hi, x_lo, wq_hi + (size_t)1024 * 1024, wq_lo + (size_t)1024 * 1024, S_ * B_, 1024, 1024, 1024,
        b_perm + 1024, nullptr, k_hi, k_lo, nullptr, nullptr);
    mgemm_kernel<1, 0, false><<<dim3(64, 8), blk, 0, stream>>>(
        x_hi, nullptr, wq_hi + (size_t)2048 * 1024, nullptr, S_ * B_, 1024, 1024, 1024,
        b_perm + 2048, nullptr, v_hi, nullptr, nullptr, nullptr);
    // 1b. V^T for attention (x_hi now dead -> v_t alias)
    vt_kernel<<<2048, blk, 0, stream>>>(v_hi, v_t);
    // 2. compression
    mgemm_kernel<3, 1, false><<<dim3(64, 8), blk, 0, stream>>>(
        k_hi, k_lo, w1h, w1l, B_ * S_, 1024, 1024, 1032,
        b_c1, rg, nullptr, nullptr, pos, w_c1);
    block_mean_kernel<<<B_ * NB_, blk, 0, stream>>>(rg, cpre_k);
    mgemm_kernel<1, 1, false><<<dim3(64, 8), blk, 0, stream>>>(
        v_hi, nullptr, w1h, nullptr, B_ * S_, 1024, 1024, 1032,
        b_c1, rg, nullptr, nullptr, pos, w_c1);
    block_mean_kernel<<<B_ * NB_, blk, 0, stream>>>(rg, cpre_v);
    split_kernel<<<508, blk, 0, stream>>>(cpre_k, cpk_hi, cpk_lo, (int)(NCMP / 4));
    split_kernel<<<508, blk, 0, stream>>>(cpre_v, cpv_hi, nullptr, (int)(NCMP / 4));
    mgemm_kernel<3, 2, false><<<dim3(4, 8), blk, 0, stream>>>(
        cpk_hi, cpk_lo, w2h, w2l, B_ * NB_, 1024, 1024, 1024,
        b_c2, cmp_k, nullptr, nullptr, nullptr, nullptr);
    mgemm_kernel<1, 2, false><<<dim3(4, 8), blk, 0, stream>>>(
        cpv_hi, nullptr, w2h, nullptr, B_ * NB_, 1024, 1024, 1024,
        b_c2, cmp_v, nullptr, nullptr, nullptr, nullptr);
    // 3. means
    mean_qs_kernel<<<B_ * H_, blk, 0, stream>>>(q_hi, q_mean_s);
    mean_qh_kernel<<<B_ * S_, 64, 0, stream>>>(q_hi, q_lo, q_mean_h);
    mean_ckh_kernel<<<B_ * NB_, 64, 0, stream>>>(cmp_k, ckm);
    // 4. compressed-branch attention + importance (fp64) + top-k
    out_cmp_kernel<<<B_ * H_, 128, 0, stream>>>(q_mean_s, cmp_k, cmp_v, ocmp);
    imp1_kernel<<<B_ * S_, 128, 0, stream>>>(q_mean_h, ckm, imp_all);
    imp2_kernel<<<B_ * NB_, 256, 0, stream>>>(imp_all, imp);
    topk_kernel<<<1, 64, 0, stream>>>(imp, topb);
    // 5. selected + window attention (MFMA flash, bf16)
    attn_mfma_kernel<16, 1><<<2048, blk, 0, stream>>>(q_hi, k_hi, v_t, topb, o_slc);
    attn_mfma_kernel<8, 0><<<2048, blk, 0, stream>>>(q_hi, k_hi, v_t, nullptr, o_win);
    // 6. gate + combine
    gate_kernel<<<B_ * S_, 128, 0, stream>>>(ocmp, o_slc, o_win, w_g, b_g, out);
}